// Round 9
// baseline (620.174 us; speedup 1.0000x reference)
//
#include <hip/hip_runtime.h>

typedef unsigned short u16;
typedef unsigned int   u32;
typedef __bf16 bf16x8 __attribute__((ext_vector_type(8)));
typedef float  f32x4  __attribute__((ext_vector_type(4)));
typedef u32    u32x4v __attribute__((ext_vector_type(4)));

#define NS 256              // samples (M)
#define KF 10000            // features (K)
#define KP 10048            // padded K
#define NO 15000            // outputs (N)
#define NP 15104            // padded N = 236*64
#define BM 128
#define BN 64
#define BK 32
#define KHALF (KP/2)        // 5024
#define NSTEPS (KHALF/BK)   // 157
#define COVR 150
#define NA 100

// ---------------- prep: BatchNorm affine + fp32 -> bf16 hi/lo split ----------------
__global__ void k_prep_x(const float* __restrict__ x, const float* __restrict__ gamma,
                         const float* __restrict__ beta, const float* __restrict__ rmean,
                         const float* __restrict__ rvar,
                         u16* __restrict__ xnh, u16* __restrict__ xnl)
{
    int k = blockIdx.x * 256 + threadIdx.x;
    int s = blockIdx.y;
    if (k >= KP) return;
    float v = 0.0f;
    if (k < KF) {
        float xv = x[(size_t)s * KF + k];
        v = (xv - rmean[k]) * (gamma[k] * rsqrtf(rvar[k] + 1e-5f)) + beta[k];
    }
    u32 bits = __float_as_uint(v);
    u32 hb   = bits & 0xffff0000u;
    float lo = v - __uint_as_float(hb);
    xnh[(size_t)s * KP + k] = (u16)(hb >> 16);
    xnl[(size_t)s * KP + k] = (u16)(__float_as_uint(lo) >> 16);
}

__device__ __forceinline__ void split_pack(float v0, float v1, u32& hp, u32& lp)
{
    u32 b0 = __float_as_uint(v0), b1 = __float_as_uint(v1);
    u32 h0 = b0 & 0xffff0000u,   h1 = b1 & 0xffff0000u;
    hp = (h0 >> 16) | h1;
    float r0 = v0 - __uint_as_float(h0);
    float r1 = v1 - __uint_as_float(h1);
    lp = (__float_as_uint(r0) >> 16) | (__float_as_uint(r1) & 0xffff0000u);
}

__device__ __forceinline__ void gload16(const u16* g, u16* l)
{
    __builtin_amdgcn_global_load_lds(
        (const __attribute__((address_space(1))) void*)g,
        (__attribute__((address_space(3))) void*)l, 16, 0, 0);
}

// ---------------- GEMM: Yp[ks] = Xn * W^T (3-term bf16 split) ----------------
// Tile 128x64, 256 thr (4 waves, wave tile 64x32), BK=32, dbuf LDS 48KB.
// Grid 944 = 236(n) x 2(K-split) x 2(M-split) -> 3 blocks/CU (12 waves/CU).
// r4-proven schedule: one barrier/step, counted vmcnt(2), A via global_load_lds,
// W reg-staged one step ahead. Quadrant-major XCD swizzle (X L2-fit per XCD).
__global__ __launch_bounds__(256, 3) void k_gemm(
    const u16* __restrict__ xnh, const u16* __restrict__ xnl,
    const float* __restrict__ W, float* __restrict__ Yp)
{
    __shared__ u16 Ah[2][BM * BK];
    __shared__ u16 Al[2][BM * BK];
    __shared__ u16 Bh[2][BN * BK];
    __shared__ u16 Bl[2][BN * BK];

    const int t = threadIdx.x;
    const int wv = t >> 6;

    // bijective XCD chunk swizzle (944 = 8*118), quadrant-major decode
    const int bid = blockIdx.x;
    const int swz = (bid & 7) * 118 + (bid >> 3);
    const int q   = swz / 236;
    const int n_idx = swz - q * 236;
    const int ks = q & 1;
    const int mh = q >> 1;
    const int n0 = n_idx * BN;
    const int kbeg = ks * KHALF;

    // A staging: thread t -> LDS slots t and t+256 (16B each), pre-swizzled global chunk
    const int rA = t >> 2;                       // rows 0..63 (+64 for slot 2)
    const int cA = (t & 3) ^ ((rA >> 1) & 3);
    const size_t eA0 = (size_t)(mh * BM + rA) * KP + cA * 8;
    const size_t eA1 = eA0 + (size_t)64 * KP;

    // W staging: thread t -> row rB (4 thr/row), swizzled 8-elem chunk cB
    const int rB = t >> 2;
    const int cB = (t & 3) ^ ((rB >> 1) & 3);
    const int oW = n0 + rB;
    const bool oOk = (oW < NO);
    const size_t eW = (size_t)(oOk ? oW : 0) * KF + cB * 8;

    // compute-side lane constants
    const int lane = t & 63;
    const int wm = wv & 1;      // 2 M-groups of 64
    const int wn = wv >> 1;     // 2 N-groups of 32
    const int l15 = lane & 15;
    const int lc  = lane >> 4;
    const int qq  = (l15 >> 1) & 3;
    const int eoff = l15 * BK + ((lc ^ qq) << 3);   // swizzled elem offset within 16-row group

    f32x4 acc[4][2];
#pragma unroll
    for (int m = 0; m < 4; ++m)
#pragma unroll
        for (int n = 0; n < 2; ++n) { acc[m][n][0]=0.f; acc[m][n][1]=0.f; acc[m][n][2]=0.f; acc[m][n][3]=0.f; }

    auto issueA = [&](int nb, int sIdx) {
        const int kk = kbeg + sIdx * BK;
        gload16(xnh + eA0 + kk, Ah[nb] + t * 8);
        gload16(xnh + eA1 + kk, Ah[nb] + 2048 + t * 8);
        gload16(xnl + eA0 + kk, Al[nb] + t * 8);
        gload16(xnl + eA1 + kk, Al[nb] + 2048 + t * 8);
    };
    auto loadW = [&](int sIdx, f32x4& w0, f32x4& w1, float& msk) {
        const int kk = kbeg + sIdx * BK;
        const bool okk = oOk && (kk + cB * 8 + 8 <= KF);
        const size_t wofs = okk ? (eW + kk) : 0;
        w0 = *(const f32x4*)(W + wofs);
        w1 = *(const f32x4*)(W + wofs + 4);
        msk = okk ? 1.f : 0.f;
    };
    auto stageB = [&](int bb, f32x4 w0, f32x4 w1, float msk) {
        w0 *= msk; w1 *= msk;
        u32 h0,p0,h1,p1,h2,p2,h3,p3;
        split_pack(w0[0], w0[1], h0, p0);
        split_pack(w0[2], w0[3], h1, p1);
        split_pack(w1[0], w1[1], h2, p2);
        split_pack(w1[2], w1[3], h3, p3);
        u32x4v hv, lv; hv[0]=h0; hv[1]=h1; hv[2]=h2; hv[3]=h3; lv[0]=p0; lv[1]=p1; lv[2]=p2; lv[3]=p3;
        ((u32x4v*)Bh[bb])[t] = hv;
        ((u32x4v*)Bl[bb])[t] = lv;
    };

    // prologue: A(0) DMA -> buf0; W(0) -> regs -> LDS buf0
    {
        issueA(0, 0);
        asm volatile("" ::: "memory");
        f32x4 w0, w1; float m0;
        loadW(0, w0, w1, m0);
        stageB(0, w0, w1, m0);     // compiler waits w regs; A DMAs stay in flight
    }

#pragma unroll 1
    for (int step = 0; step < NSTEPS; ++step) {
        const int p  = step & 1;
        const int nb = p ^ 1;
        const int sn = (step + 1 < NSTEPS) ? step + 1 : step;   // clamp (dup harmless)

        // issue next W into regs (rides across barrier)
        f32x4 nw0, nw1; float nmsk;
        loadW(sn, nw0, nw1, nmsk);

        // queue (old->new): A(step)x4, W(step+1)x2 -> drain A(step) only
        asm volatile("s_waitcnt vmcnt(2) lgkmcnt(0)" ::: "memory");
        __builtin_amdgcn_s_barrier();
        asm volatile("" ::: "memory");

        issueA(nb, sn);
        asm volatile("" ::: "memory");

        const u16* AhL = Ah[p]; const u16* AlL = Al[p];
        const u16* BhL = Bh[p]; const u16* BlL = Bl[p];

        bf16x8 fah[4], fal[4], fbh[2], fbl[2];
#pragma unroll
        for (int m = 0; m < 4; ++m) {
            const int off = (wm * 64 + m * 16) * BK + eoff;
            fah[m] = *(const bf16x8*)(AhL + off);
            fal[m] = *(const bf16x8*)(AlL + off);
        }
#pragma unroll
        for (int n = 0; n < 2; ++n) {
            const int off = (wn * 32 + n * 16) * BK + eoff;
            fbh[n] = *(const bf16x8*)(BhL + off);
            fbl[n] = *(const bf16x8*)(BlL + off);
        }

        __builtin_amdgcn_s_setprio(1);
#pragma unroll
        for (int m = 0; m < 4; ++m)
#pragma unroll
            for (int n = 0; n < 2; ++n) {
                acc[m][n] = __builtin_amdgcn_mfma_f32_16x16x32_bf16(fah[m], fbh[n], acc[m][n], 0, 0, 0);
                acc[m][n] = __builtin_amdgcn_mfma_f32_16x16x32_bf16(fah[m], fbl[n], acc[m][n], 0, 0, 0);
                acc[m][n] = __builtin_amdgcn_mfma_f32_16x16x32_bf16(fal[m], fbh[n], acc[m][n], 0, 0, 0);
            }
        __builtin_amdgcn_s_setprio(0);

        stageB(nb, nw0, nw1, nmsk);   // compiler waits W(step+1), keeps A(step+1) in flight
    }

    // epilogue: C/D layout col = lane&15, row = (lane>>4)*4 + reg
    const int rowb = mh * BM + wm * 64 + lc * 4;
    const int colb = n0 + wn * 32 + l15;
#pragma unroll
    for (int m = 0; m < 4; ++m)
#pragma unroll
        for (int n = 0; n < 2; ++n) {
            const size_t base = ((size_t)(ks * NS + rowb + m * 16)) * NP + colb + n * 16;
            Yp[base]          = acc[m][n][0];
            Yp[base + NP]     = acc[m][n][1];
            Yp[base + 2*NP]   = acc[m][n][2];
            Yp[base + 3*NP]   = acc[m][n][3];
        }
}

// ---------------- per-sample: fused (reduce+bias+relu) -> cov -> chol -> w ----------------
// 256 thr, 13x13 grid of 8x8 register tiles; all cov LDS reads are aligned f32x4.
// Single-pass raw second moment + mean correction. Cholesky 1 barrier/col, static-index
// publish. Triangular solves: single wave, shuffle broadcast.  (unchanged from r8)
__global__ __launch_bounds__(256, 1) void k_solve(const float* __restrict__ Yp,
                                                  const float* __restrict__ bias,
                                                  float* __restrict__ out)
{
    __shared__ float Ylds[15008];
    __shared__ float Lsh[10400];        // L col-major: Lsh[j*104 + row]
    __shared__ float mu[112];
    __shared__ float dgi[112];
    __shared__ float usol[112];
    __shared__ float colbuf[2][112];
    __shared__ float redv[2];

    const int s = blockIdx.x;
    const int t = threadIdx.x;

    const f32x4* y04 = (const f32x4*)(Yp + (size_t)s * NP);
    const f32x4* y14 = (const f32x4*)(Yp + (size_t)(NS + s) * NP);
    const f32x4* b4  = (const f32x4*)bias;
    for (int i = t; i < 3750; i += 256) {
        f32x4 v = y04[i] + y14[i] + b4[i];
        f32x4 r;
        r[0] = fmaxf(v[0], 0.f); r[1] = fmaxf(v[1], 0.f);
        r[2] = fmaxf(v[2], 0.f); r[3] = fmaxf(v[3], 0.f);
        *(f32x4*)&Ylds[i * 4] = r;
    }
    if (t < 8) Ylds[15000 + t] = 0.f;
    if (t >= 100 && t < 112) mu[t] = 0.f;
    __syncthreads();

    if (t < NA) {
        float a = 0.f;
        for (int r = 0; r < COVR; ++r) a += Ylds[r * NA + t];
        mu[t] = a * (1.0f / COVR);
    }
    __syncthreads();

    const int ai = t >> 4;
    const int bj = t & 15;
    const int r0 = ai * 8;
    const int c0 = bj * 8;
    const bool act = (ai < 13) && (bj < 13);

    float A[8][8];
#pragma unroll
    for (int i = 0; i < 8; ++i)
#pragma unroll
        for (int j = 0; j < 8; ++j) A[i][j] = 0.f;

    if (act) {
        for (int r = 0; r < COVR; ++r) {
            const f32x4 mi0 = *(const f32x4*)&Ylds[r * NA + r0];
            const f32x4 mi1 = *(const f32x4*)&Ylds[r * NA + r0 + 4];
            const f32x4 mj0 = *(const f32x4*)&Ylds[r * NA + c0];
            const f32x4 mj1 = *(const f32x4*)&Ylds[r * NA + c0 + 4];
            float mi[8] = {mi0[0], mi0[1], mi0[2], mi0[3], mi1[0], mi1[1], mi1[2], mi1[3]};
            float mj[8] = {mj0[0], mj0[1], mj0[2], mj0[3], mj1[0], mj1[1], mj1[2], mj1[3]};
#pragma unroll
            for (int i = 0; i < 8; ++i)
#pragma unroll
                for (int j = 0; j < 8; ++j) A[i][j] += mi[i] * mj[j];
        }
        float mui[8], muj[8];
#pragma unroll
        for (int i = 0; i < 8; ++i) mui[i] = mu[r0 + i];
#pragma unroll
        for (int j = 0; j < 8; ++j) muj[j] = mu[c0 + j];
#pragma unroll
        for (int i = 0; i < 8; ++i)
#pragma unroll
            for (int j = 0; j < 8; ++j)
                A[i][j] = (A[i][j] - (float)COVR * mui[i] * muj[j]) * (1.0f / 149.0f);
    }
    if (bj == 0 && ai < 13) {
#pragma unroll
        for (int i = 0; i < 8; ++i) colbuf[0][r0 + i] = A[i][0];
    }
    __syncthreads();

    for (int j = 0; j < NA; ++j) {
        const int cb = j & 1;
        const float d = sqrtf(colbuf[cb][j]);
        const float dinv = 1.0f / d;
        if (t == 0) dgi[j] = dinv;

        if (act) {
            float Lr[8], Lc[8];
#pragma unroll
            for (int i = 0; i < 8; ++i) {
                const int row = r0 + i;
                const float cv = colbuf[cb][row];
                Lr[i] = (row > j) ? cv * dinv : (row == j ? d : 0.f);
            }
#pragma unroll
            for (int k = 0; k < 8; ++k) {
                const int col = c0 + k;
                const float cv = colbuf[cb][col];
                Lc[k] = (col > j) ? cv * dinv : (col == j ? d : 0.f);
            }
#pragma unroll
            for (int i = 0; i < 8; ++i)
#pragma unroll
                for (int k = 0; k < 8; ++k) A[i][k] -= Lr[i] * Lc[k];

            if (bj == (j >> 3)) {
#pragma unroll
                for (int i = 0; i < 8; ++i) Lsh[j * 104 + r0 + i] = Lr[i];
            }
            if (j + 1 < NA) {
                if (bj == ((j + 1) >> 3)) {
                    const int jc = (j + 1) & 7;
#pragma unroll
                    for (int k = 0; k < 8; ++k) {
                        if (k == jc) {
#pragma unroll
                            for (int i = 0; i < 8; ++i) colbuf[cb ^ 1][r0 + i] = A[i][k];
                        }
                    }
                }
            }
        }
        __syncthreads();
    }

    if (t < 64) {
        float r0c = 1.f, r1c = 1.f;
        float y0c = 0.f, y1c = 0.f;
        for (int j = 0; j < NA; ++j) {
            const float dj = dgi[j];
            float src = (j < 64) ? __shfl(r0c, j) : __shfl(r1c, j - 64);
            const float yj = src * dj;
            if (t == j) y0c = yj;
            if (t + 64 == j) y1c = yj;
            const float l0 = Lsh[j * 104 + t];
            const float l1 = Lsh[j * 104 + t + 64];
            if (t > j) r0c -= l0 * yj;
            if (t < 36 && t + 64 > j) r1c -= l1 * yj;
        }
        float u0c = 0.f, u1c = 0.f;
        for (int j = NA - 1; j >= 0; --j) {
            const float dj = dgi[j];
            float src = (j >= 64) ? __shfl(y1c, j - 64) : __shfl(y0c, j);
            const float uj = src * dj;
            if (t == j) u0c = uj;
            if (t + 64 == j) u1c = uj;
            const float l0 = Lsh[t * 104 + j];
            const float l1 = Lsh[(t + 64) * 104 + j];
            if (t < j) y0c -= l0 * uj;
            if (t < 36 && t + 64 < j) y1c -= l1 * uj;
        }
        usol[t] = u0c;
        if (t < 36) usol[t + 64] = u1c;
        float v = u0c + ((t < 36) ? u1c : 0.f);
        for (int off = 32; off > 0; off >>= 1) v += __shfl_xor(v, off);
        if (t == 0) redv[0] = 1.0f / v;
    }
    __syncthreads();
    if (t < NA) out[s * NA + t] = usol[t] * redv[0];
}

// ---------------- launcher ----------------
extern "C" void kernel_launch(void* const* d_in, const int* in_sizes, int n_in,
                              void* d_out, int out_size, void* d_ws, size_t ws_size,
                              hipStream_t stream)
{
    const float* x     = (const float*)d_in[0];
    const float* gamma = (const float*)d_in[1];
    const float* beta  = (const float*)d_in[2];
    const float* rm    = (const float*)d_in[3];
    const float* rv    = (const float*)d_in[4];
    const float* W     = (const float*)d_in[5];
    const float* b     = (const float*)d_in[6];
    float* out = (float*)d_out;

    char* ws = (char*)d_ws;
    u16*   xnh = (u16*)ws;                              // 5,144,576 B
    u16*   xnl = (u16*)(ws + 5144576);                  // 5,144,576 B
    float* Yp  = (float*)(ws + 10289152);               // 30,932,992 B
    (void)in_sizes; (void)n_in; (void)out_size; (void)ws_size;

    k_prep_x<<<dim3(40, NS), 256, 0, stream>>>(x, gamma, beta, rm, rv, xnh, xnl);
    k_gemm  <<<dim3(944), 256, 0, stream>>>(xnh, xnl, W, Yp);
    k_solve <<<dim3(NS), 256, 0, stream>>>(Yp, b, out);
}

// Round 10
// 390.632 us; speedup vs baseline: 1.5876x; 1.5876x over previous
//
#include <hip/hip_runtime.h>

typedef unsigned short u16;
typedef unsigned int   u32;
typedef __bf16 bf16x8 __attribute__((ext_vector_type(8)));
typedef float  f32x4  __attribute__((ext_vector_type(4)));
typedef u32    u32x2  __attribute__((ext_vector_type(2)));

#define NS 256              // samples (M)
#define KF 10000            // features (K)
#define KP 10048            // padded K
#define NO 15000            // outputs (N)
#define NP 15104            // padded N
#define BM 256
#define BN 128
#define BK 32
#define KHALF (KP/2)        // 5024
#define NSTEPS (KHALF/BK)   // 157
#define COVR 150
#define NA 100

// ---------------- prep: BatchNorm affine + fp32 -> bf16 hi/lo split ----------------
__global__ void k_prep_x(const float* __restrict__ x, const float* __restrict__ gamma,
                         const float* __restrict__ beta, const float* __restrict__ rmean,
                         const float* __restrict__ rvar,
                         u16* __restrict__ xnh, u16* __restrict__ xnl)
{
    int k = blockIdx.x * 256 + threadIdx.x;
    int s = blockIdx.y;
    if (k >= KP) return;
    float v = 0.0f;
    if (k < KF) {
        float xv = x[(size_t)s * KF + k];
        v = (xv - rmean[k]) * (gamma[k] * rsqrtf(rvar[k] + 1e-5f)) + beta[k];
    }
    u32 bits = __float_as_uint(v);
    u32 hb   = bits & 0xffff0000u;
    float lo = v - __uint_as_float(hb);
    xnh[(size_t)s * KP + k] = (u16)(hb >> 16);
    xnl[(size_t)s * KP + k] = (u16)(__float_as_uint(lo) >> 16);
}

__device__ __forceinline__ void split_pack(float v0, float v1, u32& hp, u32& lp)
{
    u32 b0 = __float_as_uint(v0), b1 = __float_as_uint(v1);
    u32 h0 = b0 & 0xffff0000u,   h1 = b1 & 0xffff0000u;
    hp = (h0 >> 16) | h1;
    float r0 = v0 - __uint_as_float(h0);
    float r1 = v1 - __uint_as_float(h1);
    lp = (__float_as_uint(r0) >> 16) | (__float_as_uint(r1) & 0xffff0000u);
}

__device__ __forceinline__ void gload16(const u16* g, u16* l)
{
    __builtin_amdgcn_global_load_lds(
        (const __attribute__((address_space(1))) void*)g,
        (__attribute__((address_space(3))) void*)l, 16, 0, 0);
}

// ---------------- GEMM (r5-best, byte-identical): Yp[ks] = Xn * W^T, split-K=2 --------
// 1024 thr (16 waves, 4M x 4N, wave tile 64x32), BM=256 x BN=128, BK=32, dbuf LDS 96KB.
// ONE barrier/step, counted vmcnt(1); A via global_load_lds, W reg-staged early.
__global__ __launch_bounds__(1024, 4) void k_gemm(
    const u16* __restrict__ xnh, const u16* __restrict__ xnl,
    const float* __restrict__ W, float* __restrict__ Yp)
{
    __shared__ u16 Ah[2][BM * BK];
    __shared__ u16 Al[2][BM * BK];
    __shared__ u16 Bh[2][BN * BK];
    __shared__ u16 Bl[2][BN * BK];

    const int t    = threadIdx.x;
    const int wv   = t >> 6;
    const int n0   = blockIdx.x * BN;
    const int ks   = blockIdx.y;
    const int kbeg = ks * KHALF;

    const int rA = t >> 2;
    const int uA = t & 3;
    const int cA = uA ^ ((rA >> 1) & 3);
    const size_t eA = (size_t)rA * KP + cA * 8;

    const int rB  = t >> 3;
    const int ch  = (t >> 1) & 3;
    const int h2  = t & 1;
    const int gc  = ch ^ ((rB >> 1) & 3);
    const int kin = gc * 8 + h2 * 4;
    const int oW  = n0 + rB;
    const bool oOk = (oW < NO);
    const size_t eW = (size_t)(oOk ? oW : 0) * KF + kin;
    const int boff = rB * 32 + ch * 8 + h2 * 4;

    const int lane = t & 63;
    const int wm   = wv & 3;
    const int wn   = wv >> 2;
    const int l15  = lane & 15;
    const int lc   = lane >> 4;
    const int q    = (l15 >> 1) & 3;
    const int eoff = l15 * BK + ((lc ^ q) << 3);

    f32x4 acc[4][2];
#pragma unroll
    for (int m = 0; m < 4; ++m)
#pragma unroll
        for (int n = 0; n < 2; ++n) { acc[m][n][0]=0.f; acc[m][n][1]=0.f; acc[m][n][2]=0.f; acc[m][n][3]=0.f; }

    auto issueA = [&](int nb, int k1) {
        gload16(xnh + eA + k1, Ah[nb] + (wv << 9));
        gload16(xnl + eA + k1, Al[nb] + (wv << 9));
    };
    auto stageB = [&](int nb, f32x4 wv4, float msk) {
        wv4 *= msk;
        u32 h0, l0, h1, l1;
        split_pack(wv4[0], wv4[1], h0, l0);
        split_pack(wv4[2], wv4[3], h1, l1);
        u32x2 hv; hv[0] = h0; hv[1] = h1;
        u32x2 lv; lv[0] = l0; lv[1] = l1;
        *(u32x2*)(Bh[nb] + boff) = hv;
        *(u32x2*)(Bl[nb] + boff) = lv;
    };

    {
        issueA(0, kbeg);
        asm volatile("" ::: "memory");
        const bool okk = oOk && (kbeg + kin + 4 <= KF);
        const size_t wofs = okk ? (eW + kbeg) : 0;
        f32x4 w0 = *(const f32x4*)(W + wofs);
        stageB(0, w0, okk ? 1.f : 0.f);
    }

#pragma unroll 1
    for (int step = 0; step < NSTEPS; ++step) {
        const int p  = step & 1;
        const int nb = p ^ 1;
        const bool hasNext = (step + 1) < NSTEPS;
        const int k1 = kbeg + (step + 1) * BK;

        f32x4 nw; float nmsk = 0.f;
        if (hasNext) {
            const bool okk = oOk && (k1 + kin + 4 <= KF);
            const size_t wofs = okk ? (eW + k1) : 0;
            nw = *(const f32x4*)(W + wofs);
            nmsk = okk ? 1.f : 0.f;
        }

        if (hasNext) { asm volatile("s_waitcnt vmcnt(1) lgkmcnt(0)" ::: "memory"); }
        else         { asm volatile("s_waitcnt vmcnt(0) lgkmcnt(0)" ::: "memory"); }
        __builtin_amdgcn_s_barrier();
        asm volatile("" ::: "memory");

        if (hasNext) { issueA(nb, k1); asm volatile("" ::: "memory"); }

        const u16* AhL = Ah[p]; const u16* AlL = Al[p];
        const u16* BhL = Bh[p]; const u16* BlL = Bl[p];

        bf16x8 fah[4], fal[4], fbh[2], fbl[2];
#pragma unroll
        for (int m = 0; m < 4; ++m) {
            const int off = (wm * 64 + m * 16) * BK + eoff;
            fah[m] = *(const bf16x8*)(AhL + off);
            fal[m] = *(const bf16x8*)(AlL + off);
        }
#pragma unroll
        for (int n = 0; n < 2; ++n) {
            const int off = (wn * 32 + n * 16) * BK + eoff;
            fbh[n] = *(const bf16x8*)(BhL + off);
            fbl[n] = *(const bf16x8*)(BlL + off);
        }

        __builtin_amdgcn_s_setprio(1);
#pragma unroll
        for (int m = 0; m < 4; ++m)
#pragma unroll
            for (int n = 0; n < 2; ++n) {
                acc[m][n] = __builtin_amdgcn_mfma_f32_16x16x32_bf16(fah[m], fbh[n], acc[m][n], 0, 0, 0);
                acc[m][n] = __builtin_amdgcn_mfma_f32_16x16x32_bf16(fah[m], fbl[n], acc[m][n], 0, 0, 0);
                acc[m][n] = __builtin_amdgcn_mfma_f32_16x16x32_bf16(fal[m], fbh[n], acc[m][n], 0, 0, 0);
            }
        __builtin_amdgcn_s_setprio(0);

        if (hasNext) stageB(nb, nw, nmsk);
    }

    const int rowb = wm * 64 + lc * 4;
    const int colb = n0 + wn * 32 + l15;
#pragma unroll
    for (int m = 0; m < 4; ++m)
#pragma unroll
        for (int n = 0; n < 2; ++n) {
            const size_t base = ((size_t)(ks * NS + rowb + m * 16)) * NP + colb + n * 16;
            Yp[base]          = acc[m][n][0];
            Yp[base + NP]     = acc[m][n][1];
            Yp[base + 2*NP]   = acc[m][n][2];
            Yp[base + 3*NP]   = acc[m][n][3];
        }
}

// ---------------- per-sample: fused (reduce+bias+relu) -> cov -> blocked chol -> w -----
// 256 thr. Cov in 8x8 reg tiles (13x13). Cholesky: 8-col panels, 3 barriers/panel (39
// total vs ~100): publish panel -> redundant 8x8 diag chol in regs (LDS broadcast) ->
// per-thread forward-sub of own rows -> rank-8 register update. Junk cols/rows >=100
// re-patched to identity each panel (all values stay finite). Solves: single wave.
__global__ __launch_bounds__(256, 1) void k_solve(const float* __restrict__ Yp,
                                                  const float* __restrict__ bias,
                                                  float* __restrict__ out)
{
    __shared__ float Ylds[15008];
    __shared__ float Lsh[104 * 104];    // col-major: Lsh[col*104 + row]
    __shared__ float Lpan[104][8];      // current L panel, row-major
    __shared__ float panelbuf[104][8];  // published A panel
    __shared__ float mu[112];
    __shared__ float dgi[112];
    __shared__ float usol[112];
    __shared__ float redv[2];

    const int s = blockIdx.x;
    const int t = threadIdx.x;

    // fused split-K reduce + bias + relu into LDS (vectorized)
    const f32x4* y04 = (const f32x4*)(Yp + (size_t)s * NP);
    const f32x4* y14 = (const f32x4*)(Yp + (size_t)(NS + s) * NP);
    const f32x4* b4  = (const f32x4*)bias;
    for (int i = t; i < 3750; i += 256) {
        f32x4 v = y04[i] + y14[i] + b4[i];
        f32x4 r;
        r[0] = fmaxf(v[0], 0.f); r[1] = fmaxf(v[1], 0.f);
        r[2] = fmaxf(v[2], 0.f); r[3] = fmaxf(v[3], 0.f);
        *(f32x4*)&Ylds[i * 4] = r;
    }
    if (t < 8) Ylds[15000 + t] = 0.f;
    if (t >= 100 && t < 112) mu[t] = 0.f;
    __syncthreads();

    // column means
    if (t < NA) {
        float a = 0.f;
        for (int r = 0; r < COVR; ++r) a += Ylds[r * NA + t];
        mu[t] = a * (1.0f / COVR);
    }
    __syncthreads();

    // cov in 8x8 register tiles: A = (S - 150 mu mu^T)/149
    const int ai = t >> 4;
    const int bj = t & 15;
    const int r0 = ai * 8;
    const int c0 = bj * 8;
    const bool act = (ai < 13) && (bj < 13);

    float A[8][8];
#pragma unroll
    for (int i = 0; i < 8; ++i)
#pragma unroll
        for (int j = 0; j < 8; ++j) A[i][j] = 0.f;

    if (act) {
        for (int r = 0; r < COVR; ++r) {
            const f32x4 mi0 = *(const f32x4*)&Ylds[r * NA + r0];
            const f32x4 mi1 = *(const f32x4*)&Ylds[r * NA + r0 + 4];
            const f32x4 mj0 = *(const f32x4*)&Ylds[r * NA + c0];
            const f32x4 mj1 = *(const f32x4*)&Ylds[r * NA + c0 + 4];
            float mi[8] = {mi0[0], mi0[1], mi0[2], mi0[3], mi1[0], mi1[1], mi1[2], mi1[3]};
            float mj[8] = {mj0[0], mj0[1], mj0[2], mj0[3], mj1[0], mj1[1], mj1[2], mj1[3]};
#pragma unroll
            for (int i = 0; i < 8; ++i)
#pragma unroll
                for (int j = 0; j < 8; ++j) A[i][j] += mi[i] * mj[j];
        }
        float mui[8], muj[8];
#pragma unroll
        for (int i = 0; i < 8; ++i) mui[i] = mu[r0 + i];
#pragma unroll
        for (int j = 0; j < 8; ++j) muj[j] = mu[c0 + j];
#pragma unroll
        for (int i = 0; i < 8; ++i)
#pragma unroll
            for (int j = 0; j < 8; ++j)
                A[i][j] = (A[i][j] - (float)COVR * mui[i] * muj[j]) * (1.0f / 149.0f);
        // identity-patch the padded region (rows/cols >= 100)
#pragma unroll
        for (int i = 0; i < 8; ++i)
#pragma unroll
            for (int j = 0; j < 8; ++j)
                if (r0 + i >= NA || c0 + j >= NA)
                    A[i][j] = (r0 + i == c0 + j) ? 1.f : 0.f;
    }

    // blocked Cholesky: 13 panels of 8 columns
    for (int p = 0; p < 13; ++p) {
        // epoch 1: owners publish their (updated) col-block
        if (act && bj == p) {
#pragma unroll
            for (int i = 0; i < 8; ++i) {
                f32x4 v0, v1;
                v0[0]=A[i][0]; v0[1]=A[i][1]; v0[2]=A[i][2]; v0[3]=A[i][3];
                v1[0]=A[i][4]; v1[1]=A[i][5]; v1[2]=A[i][6]; v1[3]=A[i][7];
                *(f32x4*)&panelbuf[r0 + i][0] = v0;
                *(f32x4*)&panelbuf[r0 + i][4] = v1;
            }
        }
        __syncthreads();

        // epoch 2: redundant 8x8 diag chol in registers (broadcast LDS reads)
        float Ld[8][8];
        float Linv[8];
#pragma unroll
        for (int k = 0; k < 8; ++k) {
            float sd = panelbuf[p * 8 + k][k];
#pragma unroll
            for (int u = 0; u < 8; ++u) if (u < k) sd -= Ld[k][u] * Ld[k][u];
            const float dk = sqrtf(sd);
            Ld[k][k] = dk;
            const float inv = 1.0f / dk;
            Linv[k] = inv;
#pragma unroll
            for (int i2 = 0; i2 < 8; ++i2) if (i2 > k) {
                float s2 = panelbuf[p * 8 + i2][k];
#pragma unroll
                for (int u = 0; u < 8; ++u) if (u < k) s2 -= Ld[i2][u] * Ld[k][u];
                Ld[i2][k] = s2 * inv;
            }
        }

        // per-thread forward-sub of own 8 rows against Ld
        float Lr[8][8];
        if (act) {
#pragma unroll
            for (int i = 0; i < 8; ++i) {
#pragma unroll
                for (int m = 0; m < 8; ++m) {
                    float sv = panelbuf[r0 + i][m];
#pragma unroll
                    for (int u = 0; u < 8; ++u) if (u < m) sv -= Lr[i][u] * Ld[m][u];
                    Lr[i][m] = sv * Linv[m];
                }
            }
        }
        // writers: bj==0 publishes Lpan (row-major) + Lsh (col-major); t==0 writes dgi
        if (act && bj == 0) {
#pragma unroll
            for (int i = 0; i < 8; ++i) {
                f32x4 v0, v1;
                v0[0]=Lr[i][0]; v0[1]=Lr[i][1]; v0[2]=Lr[i][2]; v0[3]=Lr[i][3];
                v1[0]=Lr[i][4]; v1[1]=Lr[i][5]; v1[2]=Lr[i][6]; v1[3]=Lr[i][7];
                *(f32x4*)&Lpan[r0 + i][0] = v0;
                *(f32x4*)&Lpan[r0 + i][4] = v1;
            }
#pragma unroll
            for (int m = 0; m < 8; ++m)
#pragma unroll
                for (int i = 0; i < 8; ++i)
                    Lsh[(p * 8 + m) * 104 + (r0 + i)] = Lr[i][m];
        }
        if (t == 0) {
#pragma unroll
            for (int m = 0; m < 8; ++m) dgi[p * 8 + m] = Linv[m];
        }
        __syncthreads();

        // epoch 3: rank-8 update from Lpan
        if (act) {
#pragma unroll
            for (int k = 0; k < 8; ++k) {
                const f32x4 cv0 = *(const f32x4*)&Lpan[c0 + k][0];
                const f32x4 cv1 = *(const f32x4*)&Lpan[c0 + k][4];
                float Lck[8] = {cv0[0], cv0[1], cv0[2], cv0[3], cv1[0], cv1[1], cv1[2], cv1[3]};
#pragma unroll
                for (int i = 0; i < 8; ++i) {
                    float acc2 = 0.f;
#pragma unroll
                    for (int m = 0; m < 8; ++m) acc2 += Lr[i][m] * Lck[m];
                    A[i][k] -= acc2;
                }
            }
            // re-patch padded region so garbage never grows
#pragma unroll
            for (int i = 0; i < 8; ++i)
#pragma unroll
                for (int j = 0; j < 8; ++j)
                    if (r0 + i >= NA || c0 + j >= NA)
                        A[i][j] = (r0 + i == c0 + j) ? 1.f : 0.f;
        }
        __syncthreads();
    }

    // triangular solves: wave 0 only, shuffle broadcast, no barriers
    if (t < 64) {
        float r0c = 1.f, r1c = 1.f;
        float y0c = 0.f, y1c = 0.f;
        for (int j = 0; j < NA; ++j) {
            const float dj = dgi[j];
            float src = (j < 64) ? __shfl(r0c, j) : __shfl(r1c, j - 64);
            const float yj = src * dj;
            if (t == j) y0c = yj;
            if (t + 64 == j) y1c = yj;
            const float l0 = Lsh[j * 104 + t];
            const float l1 = Lsh[j * 104 + t + 64];
            if (t > j) r0c -= l0 * yj;
            if (t < 36 && t + 64 > j) r1c -= l1 * yj;
        }
        float u0c = 0.f, u1c = 0.f;
        for (int j = NA - 1; j >= 0; --j) {
            const float dj = dgi[j];
            float src = (j >= 64) ? __shfl(y1c, j - 64) : __shfl(y0c, j);
            const float uj = src * dj;
            if (t == j) u0c = uj;
            if (t + 64 == j) u1c = uj;
            const float l0 = Lsh[t * 104 + j];
            const float l1 = Lsh[(t + 64) * 104 + j];
            if (t < j) y0c -= l0 * uj;
            if (t < 36 && t + 64 < j) y1c -= l1 * uj;
        }
        usol[t] = u0c;
        if (t < 36) usol[t + 64] = u1c;
        float v = u0c + ((t < 36) ? u1c : 0.f);
        for (int off = 32; off > 0; off >>= 1) v += __shfl_xor(v, off);
        if (t == 0) redv[0] = 1.0f / v;
    }
    __syncthreads();
    if (t < NA) out[s * NA + t] = usol[t] * redv[0];
}

// ---------------- launcher ----------------
extern "C" void kernel_launch(void* const* d_in, const int* in_sizes, int n_in,
                              void* d_out, int out_size, void* d_ws, size_t ws_size,
                              hipStream_t stream)
{
    const float* x     = (const float*)d_in[0];
    const float* gamma = (const float*)d_in[1];
    const float* beta  = (const float*)d_in[2];
    const float* rm    = (const float*)d_in[3];
    const float* rv    = (const float*)d_in[4];
    const float* W     = (const float*)d_in[5];
    const float* b     = (const float*)d_in[6];
    float* out = (float*)d_out;

    char* ws = (char*)d_ws;
    u16*   xnh = (u16*)ws;                              // 5,144,576 B
    u16*   xnl = (u16*)(ws + 5144576);                  // 5,144,576 B
    float* Yp  = (float*)(ws + 10289152);               // 30,932,992 B
    (void)in_sizes; (void)n_in; (void)out_size; (void)ws_size;

    k_prep_x<<<dim3(40, NS), 256, 0, stream>>>(x, gamma, beta, rm, rv, xnh, xnl);
    k_gemm  <<<dim3(NP / BN, 2), 1024, 0, stream>>>(xnh, xnl, W, Yp);
    k_solve <<<dim3(NS), 256, 0, stream>>>(Yp, b, out);
}

// Round 12
// 372.361 us; speedup vs baseline: 1.6655x; 1.0491x over previous
//
#include <hip/hip_runtime.h>

typedef unsigned short u16;
typedef unsigned int   u32;
typedef __bf16 bf16x8 __attribute__((ext_vector_type(8)));
typedef float  f32x4  __attribute__((ext_vector_type(4)));
typedef u32    u32x2  __attribute__((ext_vector_type(2)));

#define NS 256              // samples (M)
#define KF 10000            // features (K)
#define KP 10048            // padded K
#define NO 15000            // outputs (N)
#define NP 15104            // padded N
#define BM 256
#define BN 128
#define BK 32
#define KHALF (KP/2)        // 5024
#define NSTEPS (KHALF/BK)   // 157
#define COVR 150
#define NA 100

// ---------------- prep: BatchNorm affine + fp32 -> bf16 hi/lo split ----------------
__global__ void k_prep_x(const float* __restrict__ x, const float* __restrict__ gamma,
                         const float* __restrict__ beta, const float* __restrict__ rmean,
                         const float* __restrict__ rvar,
                         u16* __restrict__ xnh, u16* __restrict__ xnl)
{
    int k = blockIdx.x * 256 + threadIdx.x;
    int s = blockIdx.y;
    if (k >= KP) return;
    float v = 0.0f;
    if (k < KF) {
        float xv = x[(size_t)s * KF + k];
        v = (xv - rmean[k]) * (gamma[k] * rsqrtf(rvar[k] + 1e-5f)) + beta[k];
    }
    u32 bits = __float_as_uint(v);
    u32 hb   = bits & 0xffff0000u;
    float lo = v - __uint_as_float(hb);
    xnh[(size_t)s * KP + k] = (u16)(hb >> 16);
    xnl[(size_t)s * KP + k] = (u16)(__float_as_uint(lo) >> 16);
}

__device__ __forceinline__ void split_pack(float v0, float v1, u32& hp, u32& lp)
{
    u32 b0 = __float_as_uint(v0), b1 = __float_as_uint(v1);
    u32 h0 = b0 & 0xffff0000u,   h1 = b1 & 0xffff0000u;
    hp = (h0 >> 16) | h1;
    float r0 = v0 - __uint_as_float(h0);
    float r1 = v1 - __uint_as_float(h1);
    lp = (__float_as_uint(r0) >> 16) | (__float_as_uint(r1) & 0xffff0000u);
}

__device__ __forceinline__ void gload16(const u16* g, u16* l)
{
    __builtin_amdgcn_global_load_lds(
        (const __attribute__((address_space(1))) void*)g,
        (__attribute__((address_space(3))) void*)l, 16, 0, 0);
}

// ---------------- GEMM: Yp[ks] = Xn * W^T (3-term bf16 split), split-K=2 --------------
// 1024 thr (16 waves, 4M x 4N, wave tile 64x32), BM=256 x BN=128, BK=32, dbuf LDS 96KB.
// Phase schedule (race-fixed): step-top {load W(s+1); vmcnt(1) retires A(s); barrier},
// then 3 phases (hh/hl/lh), each {ds_read subtile; issue 1 staging op; barrier;
// lgkmcnt(0); setprio; 8 MFMA; setprio}. W(s+1)+A(s+1) ride across all barriers;
// stageB's compiler vmcnt(2) keeps A(s+1) in flight. 4 barriers/step, no mid-loop drain.
__global__ __launch_bounds__(1024, 4) void k_gemm(
    const u16* __restrict__ xnh, const u16* __restrict__ xnl,
    const float* __restrict__ W, float* __restrict__ Yp)
{
    __shared__ u16 Ah[2][BM * BK];
    __shared__ u16 Al[2][BM * BK];
    __shared__ u16 Bh[2][BN * BK];
    __shared__ u16 Bl[2][BN * BK];

    const int t    = threadIdx.x;
    const int wv   = t >> 6;
    const int n0   = blockIdx.x * BN;
    const int ks   = blockIdx.y;
    const int kbeg = ks * KHALF;

    // A staging: thread t -> LDS slot t (16B), global chunk pre-swizzled
    const int rA = t >> 2;
    const int uA = t & 3;
    const int cA = uA ^ ((rA >> 1) & 3);
    const size_t eA = (size_t)rA * KP + cA * 8;

    // W staging: thread t -> row rB, swizzled 8-elem chunk ch, half h2 (4 f32)
    const int rB  = t >> 3;
    const int ch  = (t >> 1) & 3;
    const int h2  = t & 1;
    const int gc  = ch ^ ((rB >> 1) & 3);
    const int kin = gc * 8 + h2 * 4;
    const int oW  = n0 + rB;
    const bool oOk = (oW < NO);
    const size_t eW = (size_t)(oOk ? oW : 0) * KF + kin;
    const int boff = rB * 32 + ch * 8 + h2 * 4;

    // compute-side lane constants
    const int lane = t & 63;
    const int wm   = wv & 3;
    const int wn   = wv >> 2;
    const int l15  = lane & 15;
    const int lc   = lane >> 4;
    const int q    = (l15 >> 1) & 3;
    const int eoff = l15 * BK + ((lc ^ q) << 3);

    f32x4 acc[4][2];
#pragma unroll
    for (int m = 0; m < 4; ++m)
#pragma unroll
        for (int n = 0; n < 2; ++n) { acc[m][n][0]=0.f; acc[m][n][1]=0.f; acc[m][n][2]=0.f; acc[m][n][3]=0.f; }

    auto stageB = [&](int nb, f32x4 wv4, float msk) {
        wv4 *= msk;
        u32 h0, l0, h1, l1;
        split_pack(wv4[0], wv4[1], h0, l0);
        split_pack(wv4[2], wv4[3], h1, l1);
        u32x2 hv; hv[0] = h0; hv[1] = h1;
        u32x2 lv; lv[0] = l0; lv[1] = l1;
        *(u32x2*)(Bh[nb] + boff) = hv;
        *(u32x2*)(Bl[nb] + boff) = lv;
    };

    // prologue: A(0) DMA -> buf0; W(0) -> regs -> LDS buf0 (w0 wait drains whole queue)
    {
        gload16(xnh + eA + kbeg, Ah[0] + (wv << 9));
        gload16(xnl + eA + kbeg, Al[0] + (wv << 9));
        asm volatile("" ::: "memory");
        const bool okk = oOk && (kbeg + kin + 4 <= KF);
        const size_t wofs = okk ? (eW + kbeg) : 0;
        f32x4 w0 = *(const f32x4*)(W + wofs);
        stageB(0, w0, okk ? 1.f : 0.f);
    }

#pragma unroll 1
    for (int step = 0; step < NSTEPS; ++step) {
        const int p  = step & 1;
        const int nb = p ^ 1;
        const bool hasNext = (step + 1) < NSTEPS;
        const int k1 = kbeg + (step + 1) * BK;

        const u16* AhL = Ah[p]; const u16* AlL = Al[p];
        const u16* BhL = Bh[p]; const u16* BlL = Bl[p];

        // ===== step top: W(s+1) issue, retire A(s), collective barrier =====
        f32x4 nw; float nmsk = 0.f;
        if (hasNext) {
            const bool okk = oOk && (k1 + kin + 4 <= KF);
            const size_t wofs = okk ? (eW + k1) : 0;
            nw = *(const f32x4*)(W + wofs);           // queue: [Ahi(s), Alo(s), nw]
            nmsk = okk ? 1.f : 0.f;
            asm volatile("s_waitcnt vmcnt(1)" ::: "memory");   // retire A(s), keep nw
        } else {
            asm volatile("s_waitcnt vmcnt(0)" ::: "memory");
        }
        __builtin_amdgcn_s_barrier();                  // all waves' A(s) visible
        asm volatile("" ::: "memory");

        // ================= Phase 1: hh =================
        bf16x8 fah[4], fbh[2];
#pragma unroll
        for (int m = 0; m < 4; ++m)
            fah[m] = *(const bf16x8*)(AhL + (wm * 64 + m * 16) * BK + eoff);
#pragma unroll
        for (int n = 0; n < 2; ++n)
            fbh[n] = *(const bf16x8*)(BhL + (wn * 32 + n * 16) * BK + eoff);
        if (hasNext) {
            gload16(xnh + eA + k1, Ah[nb] + (wv << 9));   // A-hi(s+1)
            asm volatile("" ::: "memory");
        }
        __builtin_amdgcn_s_barrier();
        asm volatile("s_waitcnt lgkmcnt(0)" ::: "memory");
        __builtin_amdgcn_s_setprio(1);
#pragma unroll
        for (int m = 0; m < 4; ++m)
#pragma unroll
            for (int n = 0; n < 2; ++n)
                acc[m][n] = __builtin_amdgcn_mfma_f32_16x16x32_bf16(fah[m], fbh[n], acc[m][n], 0, 0, 0);
        __builtin_amdgcn_s_setprio(0);
        __builtin_amdgcn_sched_barrier(0);

        // ================= Phase 2: hl =================
        bf16x8 fbl[2];
#pragma unroll
        for (int n = 0; n < 2; ++n)
            fbl[n] = *(const bf16x8*)(BlL + (wn * 32 + n * 16) * BK + eoff);
        if (hasNext) {
            gload16(xnl + eA + k1, Al[nb] + (wv << 9));   // A-lo(s+1)
            asm volatile("" ::: "memory");
        }
        __builtin_amdgcn_s_barrier();
        asm volatile("s_waitcnt lgkmcnt(0)" ::: "memory");
        __builtin_amdgcn_s_setprio(1);
#pragma unroll
        for (int m = 0; m < 4; ++m)
#pragma unroll
            for (int n = 0; n < 2; ++n)
                acc[m][n] = __builtin_amdgcn_mfma_f32_16x16x32_bf16(fah[m], fbl[n], acc[m][n], 0, 0, 0);
        __builtin_amdgcn_s_setprio(0);
        __builtin_amdgcn_sched_barrier(0);

        // ================= Phase 3: lh =================
        bf16x8 fal[4];
#pragma unroll
        for (int m = 0; m < 4; ++m)
            fal[m] = *(const bf16x8*)(AlL + (wm * 64 + m * 16) * BK + eoff);
        if (hasNext) stageB(nb, nw, nmsk);   // compiler vmcnt(2) for nw; A(s+1) in flight
        __builtin_amdgcn_s_barrier();
        asm volatile("s_waitcnt lgkmcnt(0)" ::: "memory");   // fal + stageB writes drained
        __builtin_amdgcn_s_setprio(1);
#pragma unroll
        for (int m = 0; m < 4; ++m)
#pragma unroll
            for (int n = 0; n < 2; ++n)
                acc[m][n] = __builtin_amdgcn_mfma_f32_16x16x32_bf16(fal[m], fbh[n], acc[m][n], 0, 0, 0);
        __builtin_amdgcn_s_setprio(0);
        __builtin_amdgcn_sched_barrier(0);
    }

    // epilogue: C/D layout col = lane&15, row = (lane>>4)*4 + reg
    const int rowb = wm * 64 + lc * 4;
    const int colb = n0 + wn * 32 + l15;
#pragma unroll
    for (int m = 0; m < 4; ++m)
#pragma unroll
        for (int n = 0; n < 2; ++n) {
            const size_t base = ((size_t)(ks * NS + rowb + m * 16)) * NP + colb + n * 16;
            Yp[base]          = acc[m][n][0];
            Yp[base + NP]     = acc[m][n][1];
            Yp[base + 2*NP]   = acc[m][n][2];
            Yp[base + 3*NP]   = acc[m][n][3];
        }
}

// ---------------- per-sample: fused (reduce+bias+relu) -> cov -> blocked chol -> w -----
// (unchanged from r10: 39-barrier blocked Cholesky, 8x8 reg tiles, single-wave solves)
__global__ __launch_bounds__(256, 1) void k_solve(const float* __restrict__ Yp,
                                                  const float* __restrict__ bias,
                                                  float* __restrict__ out)
{
    __shared__ float Ylds[15008];
    __shared__ float Lsh[104 * 104];    // col-major: Lsh[col*104 + row]
    __shared__ float Lpan[104][8];      // current L panel, row-major
    __shared__ float panelbuf[104][8];  // published A panel
    __shared__ float mu[112];
    __shared__ float dgi[112];
    __shared__ float usol[112];
    __shared__ float redv[2];

    const int s = blockIdx.x;
    const int t = threadIdx.x;

    const f32x4* y04 = (const f32x4*)(Yp + (size_t)s * NP);
    const f32x4* y14 = (const f32x4*)(Yp + (size_t)(NS + s) * NP);
    const f32x4* b4  = (const f32x4*)bias;
    for (int i = t; i < 3750; i += 256) {
        f32x4 v = y04[i] + y14[i] + b4[i];
        f32x4 r;
        r[0] = fmaxf(v[0], 0.f); r[1] = fmaxf(v[1], 0.f);
        r[2] = fmaxf(v[2], 0.f); r[3] = fmaxf(v[3], 0.f);
        *(f32x4*)&Ylds[i * 4] = r;
    }
    if (t < 8) Ylds[15000 + t] = 0.f;
    if (t >= 100 && t < 112) mu[t] = 0.f;
    __syncthreads();

    if (t < NA) {
        float a = 0.f;
        for (int r = 0; r < COVR; ++r) a += Ylds[r * NA + t];
        mu[t] = a * (1.0f / COVR);
    }
    __syncthreads();

    const int ai = t >> 4;
    const int bj = t & 15;
    const int r0 = ai * 8;
    const int c0 = bj * 8;
    const bool act = (ai < 13) && (bj < 13);

    float A[8][8];
#pragma unroll
    for (int i = 0; i < 8; ++i)
#pragma unroll
        for (int j = 0; j < 8; ++j) A[i][j] = 0.f;

    if (act) {
        for (int r = 0; r < COVR; ++r) {
            const f32x4 mi0 = *(const f32x4*)&Ylds[r * NA + r0];
            const f32x4 mi1 = *(const f32x4*)&Ylds[r * NA + r0 + 4];
            const f32x4 mj0 = *(const f32x4*)&Ylds[r * NA + c0];
            const f32x4 mj1 = *(const f32x4*)&Ylds[r * NA + c0 + 4];
            float mi[8] = {mi0[0], mi0[1], mi0[2], mi0[3], mi1[0], mi1[1], mi1[2], mi1[3]};
            float mj[8] = {mj0[0], mj0[1], mj0[2], mj0[3], mj1[0], mj1[1], mj1[2], mj1[3]};
#pragma unroll
            for (int i = 0; i < 8; ++i)
#pragma unroll
                for (int j = 0; j < 8; ++j) A[i][j] += mi[i] * mj[j];
        }
        float mui[8], muj[8];
#pragma unroll
        for (int i = 0; i < 8; ++i) mui[i] = mu[r0 + i];
#pragma unroll
        for (int j = 0; j < 8; ++j) muj[j] = mu[c0 + j];
#pragma unroll
        for (int i = 0; i < 8; ++i)
#pragma unroll
            for (int j = 0; j < 8; ++j)
                A[i][j] = (A[i][j] - (float)COVR * mui[i] * muj[j]) * (1.0f / 149.0f);
#pragma unroll
        for (int i = 0; i < 8; ++i)
#pragma unroll
            for (int j = 0; j < 8; ++j)
                if (r0 + i >= NA || c0 + j >= NA)
                    A[i][j] = (r0 + i == c0 + j) ? 1.f : 0.f;
    }

    for (int p = 0; p < 13; ++p) {
        if (act && bj == p) {
#pragma unroll
            for (int i = 0; i < 8; ++i) {
                f32x4 v0, v1;
                v0[0]=A[i][0]; v0[1]=A[i][1]; v0[2]=A[i][2]; v0[3]=A[i][3];
                v1[0]=A[i][4]; v1[1]=A[i][5]; v1[2]=A[i][6]; v1[3]=A[i][7];
                *(f32x4*)&panelbuf[r0 + i][0] = v0;
                *(f32x4*)&panelbuf[r0 + i][4] = v1;
            }
        }
        __syncthreads();

        float Ld[8][8];
        float Linv[8];
#pragma unroll
        for (int k = 0; k < 8; ++k) {
            float sd = panelbuf[p * 8 + k][k];
#pragma unroll
            for (int u = 0; u < 8; ++u) if (u < k) sd -= Ld[k][u] * Ld[k][u];
            const float dk = sqrtf(sd);
            Ld[k][k] = dk;
            const float inv = 1.0f / dk;
            Linv[k] = inv;
#pragma unroll
            for (int i2 = 0; i2 < 8; ++i2) if (i2 > k) {
                float s2 = panelbuf[p * 8 + i2][k];
#pragma unroll
                for (int u = 0; u < 8; ++u) if (u < k) s2 -= Ld[i2][u] * Ld[k][u];
                Ld[i2][k] = s2 * inv;
            }
        }

        float Lr[8][8];
        if (act) {
#pragma unroll
            for (int i = 0; i < 8; ++i) {
#pragma unroll
                for (int m = 0; m < 8; ++m) {
                    float sv = panelbuf[r0 + i][m];
#pragma unroll
                    for (int u = 0; u < 8; ++u) if (u < m) sv -= Lr[i][u] * Ld[m][u];
                    Lr[i][m] = sv * Linv[m];
                }
            }
        }
        if (act && bj == 0) {
#pragma unroll
            for (int i = 0; i < 8; ++i) {
                f32x4 v0, v1;
                v0[0]=Lr[i][0]; v0[1]=Lr[i][1]; v0[2]=Lr[i][2]; v0[3]=Lr[i][3];
                v1[0]=Lr[i][4]; v1[1]=Lr[i][5]; v1[2]=Lr[i][6]; v1[3]=Lr[i][7];
                *(f32x4*)&Lpan[r0 + i][0] = v0;
                *(f32x4*)&Lpan[r0 + i][4] = v1;
            }
#pragma unroll
            for (int m = 0; m < 8; ++m)
#pragma unroll
                for (int i = 0; i < 8; ++i)
                    Lsh[(p * 8 + m) * 104 + (r0 + i)] = Lr[i][m];
        }
        if (t == 0) {
#pragma unroll
            for (int m = 0; m < 8; ++m) dgi[p * 8 + m] = Linv[m];
        }
        __syncthreads();

        if (act) {
#pragma unroll
            for (int k = 0; k < 8; ++k) {
                const f32x4 cv0 = *(const f32x4*)&Lpan[c0 + k][0];
                const f32x4 cv1 = *(const f32x4*)&Lpan[c0 + k][4];
                float Lck[8] = {cv0[0], cv0[1], cv0[2], cv0[3], cv1[0], cv1[1], cv1[2], cv1[3]};
#pragma unroll
                for (int i = 0; i < 8; ++i) {
                    float acc2 = 0.f;
#pragma unroll
                    for (int m = 0; m < 8; ++m) acc2 += Lr[i][m] * Lck[m];
                    A[i][k] -= acc2;
                }
            }
#pragma unroll
            for (int i = 0; i < 8; ++i)
#pragma unroll
                for (int j = 0; j < 8; ++j)
                    if (r0 + i >= NA || c0 + j >= NA)
                        A[i][j] = (r0 + i == c0 + j) ? 1.f : 0.f;
        }
        __syncthreads();
    }

    if (t < 64) {
        float r0c = 1.f, r1c = 1.f;
        float y0c = 0.f, y1c = 0.f;
        for (int j = 0; j < NA; ++j) {
            const float dj = dgi[j];
            float src = (j < 64) ? __shfl(r0c, j) : __shfl(r1c, j - 64);
            const float yj = src * dj;
            if (t == j) y0c = yj;
            if (t + 64 == j) y1c = yj;
            const float l0 = Lsh[j * 104 + t];
            const float l1 = Lsh[j * 104 + t + 64];
            if (t > j) r0c -= l0 * yj;
            if (t < 36 && t + 64 > j) r1c -= l1 * yj;
        }
        float u0c = 0.f, u1c = 0.f;
        for (int j = NA - 1; j >= 0; --j) {
            const float dj = dgi[j];
            float src = (j >= 64) ? __shfl(y1c, j - 64) : __shfl(y0c, j);
            const float uj = src * dj;
            if (t == j) u0c = uj;
            if (t + 64 == j) u1c = uj;
            const float l0 = Lsh[t * 104 + j];
            const float l1 = Lsh[(t + 64) * 104 + j];
            if (t < j) y0c -= l0 * uj;
            if (t < 36 && t + 64 < j) y1c -= l1 * uj;
        }
        usol[t] = u0c;
        if (t < 36) usol[t + 64] = u1c;
        float v = u0c + ((t < 36) ? u1c : 0.f);
        for (int off = 32; off > 0; off >>= 1) v += __shfl_xor(v, off);
        if (t == 0) redv[0] = 1.0f / v;
    }
    __syncthreads();
    if (t < NA) out[s * NA + t] = usol[t] * redv[0];
}

// ---------------- launcher ----------------
extern "C" void kernel_launch(void* const* d_in, const int* in_sizes, int n_in,
                              void* d_out, int out_size, void* d_ws, size_t ws_size,
                              hipStream_t stream)
{
    const float* x     = (const float*)d_in[0];
    const float* gamma = (const float*)d_in[1];
    const float* beta  = (const float*)d_in[2];
    const float* rm    = (const float*)d_in[3];
    const float* rv    = (const float*)d_in[4];
    const float* W     = (const float*)d_in[5];
    const float* b     = (const float*)d_in[6];
    float* out = (float*)d_out;

    char* ws = (char*)d_ws;
    u16*   xnh = (u16*)ws;                              // 5,144,576 B
    u16*   xnl = (u16*)(ws + 5144576);                  // 5,144,576 B
    float* Yp  = (float*)(ws + 10289152);               // 30,932,992 B
    (void)in_sizes; (void)n_in; (void)out_size; (void)ws_size;

    k_prep_x<<<dim3(40, NS), 256, 0, stream>>>(x, gamma, beta, rm, rv, xnh, xnl);
    k_gemm  <<<dim3(NP / BN, 2), 1024, 0, stream>>>(xnh, xnl, W, Yp);
    k_solve <<<dim3(NS), 256, 0, stream>>>(Yp, b, out);
}